// Round 1
// baseline (124.813 us; speedup 1.0000x reference)
//
#include <hip/hip_runtime.h>

#define EPS 1e-5f

typedef _Float16 half8 __attribute__((ext_vector_type(8)));
typedef float f32x4 __attribute__((ext_vector_type(4)));

// ---------------------------------------------------------------------------
// prep: fold BN into weights/biases, transpose w1 halves, cast to fp16
// ---------------------------------------------------------------------------
__global__ void prep_kernel(
    const float* __restrict__ w1, const float* __restrict__ b1,
    const float* __restrict__ g1, const float* __restrict__ be1,
    const float* __restrict__ m1, const float* __restrict__ v1,
    const float* __restrict__ w2, const float* __restrict__ b2,
    const float* __restrict__ g2, const float* __restrict__ be2,
    const float* __restrict__ m2, const float* __restrict__ v2,
    const float* __restrict__ w3, const float* __restrict__ b3,
    const float* __restrict__ g3, const float* __restrict__ be3,
    const float* __restrict__ m3, const float* __restrict__ v3,
    const float* __restrict__ w4,
    float* __restrict__ wxT, float* __restrict__ wyT, float* __restrict__ hb,
    float* __restrict__ b2f, float* __restrict__ b3f,
    _Float16* __restrict__ w2h, _Float16* __restrict__ w3h, _Float16* __restrict__ w4h)
{
    int tid = blockIdx.x * blockDim.x + threadIdx.x;
    int nth = gridDim.x * blockDim.x;

    // wxT[f][h] = alpha1[h] * w1[h][f]; wyT[f][h] = alpha1[h] * w1[h][128+f]
    for (int idx = tid; idx < 128 * 512; idx += nth) {
        int f = idx >> 9, h = idx & 511;
        float a = g1[h] * rsqrtf(v1[h] + EPS);
        wxT[idx] = a * w1[h * 256 + f];
        wyT[idx] = a * w1[h * 256 + 128 + f];
    }
    // w2h[n][k] = alpha2[n]*w2[n][k]
    for (int idx = tid; idx < 256 * 512; idx += nth) {
        int n = idx >> 9;
        float a = g2[n] * rsqrtf(v2[n] + EPS);
        w2h[idx] = (_Float16)(a * w2[idx]);
    }
    for (int idx = tid; idx < 128 * 256; idx += nth) {
        int n = idx >> 8;
        float a = g3[n] * rsqrtf(v3[n] + EPS);
        w3h[idx] = (_Float16)(a * w3[idx]);
    }
    for (int idx = tid; idx < 64 * 128; idx += nth) {
        w4h[idx] = (_Float16)w4[idx];
    }
    if (tid < 512) {
        float a = g1[tid] * rsqrtf(v1[tid] + EPS);
        hb[tid] = a * b1[tid] + be1[tid] - m1[tid] * a;
    } else if (tid < 768) {
        int n = tid - 512;
        float a = g2[n] * rsqrtf(v2[n] + EPS);
        b2f[n] = a * b2[n] + be2[n] - m2[n] * a;
    } else if (tid < 896) {
        int n = tid - 768;
        float a = g3[n] * rsqrtf(v3[n] + EPS);
        b3f[n] = a * b3[n] + be3[n] - m3[n] * a;
    }
}

// ---------------------------------------------------------------------------
// hxhy: hx[b,i,h] = x[b,i,:]·wxT[:,h] + hb[h]   (fp32)
//       hyh[b,j,h] = y[b,j,:]·wyT[:,h]          (fp16)
// grid 256 blocks x 256 threads; block = (b, 8-row group, half of h)
// ---------------------------------------------------------------------------
__global__ void hxhy_kernel(
    const float* __restrict__ x, const float* __restrict__ y,
    const float* __restrict__ wxT, const float* __restrict__ wyT,
    const float* __restrict__ hb,
    float* __restrict__ hx, _Float16* __restrict__ hyh)
{
    int bid = blockIdx.x;
    int hg = bid & 1;
    int rg = (bid >> 1) & 15;
    int b  = bid >> 5;
    int t  = threadIdx.x;
    int h  = hg * 256 + t;

    __shared__ float xs[8][128];
    __shared__ float ys[8][128];
    for (int u = t; u < 1024; u += 256) {
        int r = u >> 7, f = u & 127;
        size_t row = (size_t)(b * 128 + rg * 8 + r) * 128 + f;
        xs[r][f] = x[row];
        ys[r][f] = y[row];
    }
    __syncthreads();

    float ax[8], ay[8];
#pragma unroll
    for (int r = 0; r < 8; ++r) { ax[r] = 0.f; ay[r] = 0.f; }

    for (int f = 0; f < 128; ++f) {
        float wx = wxT[f * 512 + h];
        float wy = wyT[f * 512 + h];
#pragma unroll
        for (int r = 0; r < 8; ++r) {
            ax[r] = fmaf(xs[r][f], wx, ax[r]);
            ay[r] = fmaf(ys[r][f], wy, ay[r]);
        }
    }
    float hbv = hb[h];
#pragma unroll
    for (int r = 0; r < 8; ++r) {
        size_t o = (size_t)(b * 128 + rg * 8 + r) * 512 + h;
        hx[o]  = ax[r] + hbv;
        hyh[o] = (_Float16)ay[r];
    }
}

// ---------------------------------------------------------------------------
// fused: one block per (b, i). M = 128 (all j), MLP 512->256->128->64,
// then s = sum_j e and out[j] = sum_k e[j][k]*s[k]. 512 threads = 8 waves.
// ---------------------------------------------------------------------------
__global__ __launch_bounds__(512, 2)
void fused_kernel(
    const float* __restrict__ hx, const _Float16* __restrict__ hyh,
    const _Float16* __restrict__ w2h, const _Float16* __restrict__ w3h,
    const _Float16* __restrict__ w4h,
    const float* __restrict__ b2f, const float* __restrict__ b3f,
    const float* __restrict__ b4,
    float* __restrict__ out)
{
    constexpr int LDK = 72;   // padded k-tile row stride (halves)
    constexpr int LD2 = 264;  // a2 row stride (halves)
    constexpr int LD3 = 136;  // a3 / w4 row stride (halves)
    constexpr int LDE = 68;   // e row stride (f32)

    __shared__ char smem[127232] __attribute__((aligned(16)));
    _Float16* a1t = (_Float16*)smem;                // [128][72]  18432 B
    _Float16* w2t = (_Float16*)(smem + 18432);      // [256][72]  36864 B
    _Float16* w3t = (_Float16*)(smem + 18432);      // reuse: [128][72]
    _Float16* w4t = (_Float16*)(smem + 18432);      // reuse: [64][136]
    char* big = smem + 55296;
    _Float16* a2 = (_Float16*)big;                  // [128][264] 67584 B
    _Float16* a3 = (_Float16*)big;                  // reuse: [128][136]
    float*    es = (float*)big;                     // reuse: [128][68]
    float* hxs   = (float*)(smem + 122880);         // [512]
    float* spart = (float*)(smem + 122880 + 2048);  // [8][64]
    float* ss    = (float*)(smem + 122880 + 4096);  // [64]

    const int b = blockIdx.x >> 7;
    const int i = blockIdx.x & 127;
    const int t = threadIdx.x;
    const int wid = t >> 6;
    const int lane = t & 63;
    const int l15 = lane & 15, lg = lane >> 4;

    hxs[t] = hx[(size_t)(b * 128 + i) * 512 + t];
    __syncthreads();

    const int wm = wid >> 1, wn = wid & 1;
    const size_t hybase = (size_t)b * 128 * 512;

    // ---------------- layer 2: [128x512] @ [256x512]^T ----------------
    f32x4 acc2[2][8];
#pragma unroll
    for (int mt = 0; mt < 2; ++mt)
#pragma unroll
        for (int nt = 0; nt < 8; ++nt) acc2[mt][nt] = (f32x4)0.f;

    for (int kt = 0; kt < 8; ++kt) {
        const int k0 = kt * 64;
        // stage a1 tile [128][64]: relu(hx + hy)
        {
            int j = t >> 2, q = t & 3;
            const _Float16* src = hyh + hybase + (size_t)j * 512 + k0 + q * 16;
            half8 h0 = *(const half8*)src;
            half8 h1 = *(const half8*)(src + 8);
            half8 o0, o1;
#pragma unroll
            for (int c = 0; c < 8; ++c) {
                float v0 = hxs[k0 + q * 16 + c] + (float)h0[c];
                float v1 = hxs[k0 + q * 16 + 8 + c] + (float)h1[c];
                o0[c] = (_Float16)fmaxf(v0, 0.f);
                o1[c] = (_Float16)fmaxf(v1, 0.f);
            }
            *(half8*)(a1t + j * LDK + q * 16) = o0;
            *(half8*)(a1t + j * LDK + q * 16 + 8) = o1;
        }
        // stage w2 tile [256][64]
        {
#pragma unroll
            for (int it = 0; it < 2; ++it) {
                int cid = t + it * 512;
                int n = cid >> 2, q = cid & 3;
                const _Float16* src = w2h + (size_t)n * 512 + k0 + q * 16;
                *(half8*)(w2t + n * LDK + q * 16) = *(const half8*)src;
                *(half8*)(w2t + n * LDK + q * 16 + 8) = *(const half8*)(src + 8);
            }
        }
        __syncthreads();
#pragma unroll
        for (int kk = 0; kk < 2; ++kk) {
            const int kc = kk * 32 + lg * 8;
            half8 af[2], bf[8];
#pragma unroll
            for (int mt = 0; mt < 2; ++mt)
                af[mt] = *(const half8*)(a1t + (wm * 32 + mt * 16 + l15) * LDK + kc);
#pragma unroll
            for (int nt = 0; nt < 8; ++nt)
                bf[nt] = *(const half8*)(w2t + (wn * 128 + nt * 16 + l15) * LDK + kc);
#pragma unroll
            for (int mt = 0; mt < 2; ++mt)
#pragma unroll
                for (int nt = 0; nt < 8; ++nt)
                    acc2[mt][nt] = __builtin_amdgcn_mfma_f32_16x16x32_f16(
                        af[mt], bf[nt], acc2[mt][nt], 0, 0, 0);
        }
        __syncthreads();
    }
    // epilogue -> a2 (fp16, relu)
    {
        float bb[8];
#pragma unroll
        for (int nt = 0; nt < 8; ++nt) bb[nt] = b2f[wn * 128 + nt * 16 + l15];
#pragma unroll
        for (int mt = 0; mt < 2; ++mt)
#pragma unroll
            for (int nt = 0; nt < 8; ++nt)
#pragma unroll
                for (int r = 0; r < 4; ++r) {
                    int m = wm * 32 + mt * 16 + lg * 4 + r;
                    int n = wn * 128 + nt * 16 + l15;
                    a2[m * LD2 + n] = (_Float16)fmaxf(acc2[mt][nt][r] + bb[nt], 0.f);
                }
    }
    __syncthreads();

    // ---------------- layer 3: [128x256] @ [128x256]^T ----------------
    f32x4 acc3[2][4];
#pragma unroll
    for (int mt = 0; mt < 2; ++mt)
#pragma unroll
        for (int nt = 0; nt < 4; ++nt) acc3[mt][nt] = (f32x4)0.f;

    for (int kt = 0; kt < 4; ++kt) {
        const int k0 = kt * 64;
        {
            int n = t >> 2, q = t & 3;
            const _Float16* src = w3h + (size_t)n * 256 + k0 + q * 16;
            *(half8*)(w3t + n * LDK + q * 16) = *(const half8*)src;
            *(half8*)(w3t + n * LDK + q * 16 + 8) = *(const half8*)(src + 8);
        }
        __syncthreads();
#pragma unroll
        for (int kk = 0; kk < 2; ++kk) {
            const int kc = kk * 32 + lg * 8;
            half8 af[2], bf[4];
#pragma unroll
            for (int mt = 0; mt < 2; ++mt)
                af[mt] = *(const half8*)(a2 + (wm * 32 + mt * 16 + l15) * LD2 + k0 + kc);
#pragma unroll
            for (int nt = 0; nt < 4; ++nt)
                bf[nt] = *(const half8*)(w3t + (wn * 64 + nt * 16 + l15) * LDK + kc);
#pragma unroll
            for (int mt = 0; mt < 2; ++mt)
#pragma unroll
                for (int nt = 0; nt < 4; ++nt)
                    acc3[mt][nt] = __builtin_amdgcn_mfma_f32_16x16x32_f16(
                        af[mt], bf[nt], acc3[mt][nt], 0, 0, 0);
        }
        __syncthreads();
    }
    // epilogue -> a3 (aliases a2's storage; all reads of a2 are done)
    {
        float bb[4];
#pragma unroll
        for (int nt = 0; nt < 4; ++nt) bb[nt] = b3f[wn * 64 + nt * 16 + l15];
#pragma unroll
        for (int mt = 0; mt < 2; ++mt)
#pragma unroll
            for (int nt = 0; nt < 4; ++nt)
#pragma unroll
                for (int r = 0; r < 4; ++r) {
                    int m = wm * 32 + mt * 16 + lg * 4 + r;
                    int n = wn * 64 + nt * 16 + l15;
                    a3[m * LD3 + n] = (_Float16)fmaxf(acc3[mt][nt][r] + bb[nt], 0.f);
                }
    }
    __syncthreads();

    // ---------------- layer 4: [128x128] @ [64x128]^T ----------------
    {
        int n = t >> 3, q = t & 7;
        const _Float16* src = w4h + n * 128 + q * 16;
        *(half8*)(w4t + n * LD3 + q * 16) = *(const half8*)src;
        *(half8*)(w4t + n * LD3 + q * 16 + 8) = *(const half8*)(src + 8);
    }
    __syncthreads();

    f32x4 acc4[2][2];
#pragma unroll
    for (int mt = 0; mt < 2; ++mt)
#pragma unroll
        for (int nt = 0; nt < 2; ++nt) acc4[mt][nt] = (f32x4)0.f;

#pragma unroll
    for (int kk = 0; kk < 4; ++kk) {
        const int kc = kk * 32 + lg * 8;
        half8 af[2], bf[2];
#pragma unroll
        for (int mt = 0; mt < 2; ++mt)
            af[mt] = *(const half8*)(a3 + (wm * 32 + mt * 16 + l15) * LD3 + kc);
#pragma unroll
        for (int nt = 0; nt < 2; ++nt)
            bf[nt] = *(const half8*)(w4t + (wn * 32 + nt * 16 + l15) * LD3 + kc);
#pragma unroll
        for (int mt = 0; mt < 2; ++mt)
#pragma unroll
            for (int nt = 0; nt < 2; ++nt)
                acc4[mt][nt] = __builtin_amdgcn_mfma_f32_16x16x32_f16(
                    af[mt], bf[nt], acc4[mt][nt], 0, 0, 0);
    }
    __syncthreads();  // a3 reads done before es overwrites it
    {
        float bb[2];
#pragma unroll
        for (int nt = 0; nt < 2; ++nt) bb[nt] = b4[wn * 32 + nt * 16 + l15];
#pragma unroll
        for (int mt = 0; mt < 2; ++mt)
#pragma unroll
            for (int nt = 0; nt < 2; ++nt)
#pragma unroll
                for (int r = 0; r < 4; ++r) {
                    int m = wm * 32 + mt * 16 + lg * 4 + r;
                    int n = wn * 32 + nt * 16 + l15;
                    es[m * LDE + n] = acc4[mt][nt][r] + bb[nt];
                }
    }
    __syncthreads();

    // ---------------- s = sum_j e ; out[j] = sum_k e[j][k] * s[k] ----------------
    {
        float sv = 0.f;
#pragma unroll
        for (int jj = 0; jj < 16; ++jj) sv += es[(wid + jj * 8) * LDE + lane];
        spart[wid * 64 + lane] = sv;
    }
    __syncthreads();
    if (t < 64) {
        float sv = 0.f;
#pragma unroll
        for (int r = 0; r < 8; ++r) sv += spart[r * 64 + t];
        ss[t] = sv;
    }
    __syncthreads();
    {
        int j = t >> 2, q = t & 3;
        float p = 0.f;
#pragma unroll
        for (int c = 0; c < 16; ++c) {
            int k = q * 16 + c;
            p += es[j * LDE + k] * ss[k];
        }
        p += __shfl_xor(p, 1);
        p += __shfl_xor(p, 2);
        if (q == 0) out[(size_t)(b * 128 + i) * 128 + j] = p;
    }
}

// ---------------------------------------------------------------------------
extern "C" void kernel_launch(void* const* d_in, const int* in_sizes, int n_in,
                              void* d_out, int out_size, void* d_ws, size_t ws_size,
                              hipStream_t stream)
{
    (void)in_sizes; (void)n_in; (void)out_size; (void)ws_size;

    const float* x   = (const float*)d_in[0];
    const float* y   = (const float*)d_in[1];
    const float* w1  = (const float*)d_in[2];
    const float* b1  = (const float*)d_in[3];
    const float* g1  = (const float*)d_in[4];
    const float* be1 = (const float*)d_in[5];
    const float* m1  = (const float*)d_in[6];
    const float* v1  = (const float*)d_in[7];
    const float* w2  = (const float*)d_in[8];
    const float* b2  = (const float*)d_in[9];
    const float* g2  = (const float*)d_in[10];
    const float* be2 = (const float*)d_in[11];
    const float* m2  = (const float*)d_in[12];
    const float* v2  = (const float*)d_in[13];
    const float* w3  = (const float*)d_in[14];
    const float* b3  = (const float*)d_in[15];
    const float* g3  = (const float*)d_in[16];
    const float* be3 = (const float*)d_in[17];
    const float* m3  = (const float*)d_in[18];
    const float* v3  = (const float*)d_in[19];
    const float* w4  = (const float*)d_in[20];
    const float* b4  = (const float*)d_in[21];
    float* out = (float*)d_out;

    // workspace layout (≈3.84 MB total)
    float* wxT = (float*)d_ws;            // 128*512
    float* wyT = wxT + 65536;             // 128*512
    float* hb  = wyT + 65536;             // 512
    float* b2f = hb + 512;                // 256
    float* b3f = b2f + 256;               // 128
    float* hx  = b3f + 128;               // 8*128*512
    _Float16* w2h = (_Float16*)(hx + 524288);  // 256*512
    _Float16* w3h = w2h + 131072;              // 128*256
    _Float16* w4h = w3h + 32768;               // 64*128
    _Float16* hyh = w4h + 8192;                // 8*128*512

    hipLaunchKernelGGL(prep_kernel, dim3(64), dim3(256), 0, stream,
                       w1, b1, g1, be1, m1, v1,
                       w2, b2, g2, be2, m2, v2,
                       w3, b3, g3, be3, m3, v3,
                       w4,
                       wxT, wyT, hb, b2f, b3f, w2h, w3h, w4h);

    hipLaunchKernelGGL(hxhy_kernel, dim3(256), dim3(256), 0, stream,
                       x, y, wxT, wyT, hb, hx, hyh);

    hipLaunchKernelGGL(fused_kernel, dim3(1024), dim3(512), 0, stream,
                       hx, hyh, w2h, w3h, w4h, b2f, b3f, b4, out);
}